// Round 1
// baseline (156.721 us; speedup 1.0000x reference)
//
#include <hip/hip_runtime.h>
#include <stdint.h>

// BinConv2d: sign(x) conv3x3(pad1) sign(w) + batch-stat BN, all integer-exact via
// XNOR-popcount on 128-channel bitplanes.
//
// Sizes
#define HH 56
#define WW 56
#define CC 128
#define OO 128
#define NIMG 64
#define PIX (HH*WW)              // 3136
#define CNT (NIMG*PIX)           // 200704 per channel
#define TOT ((size_t)NIMG*OO*PIX) // 25690112

// ws layout (bytes)
//   0        wpack    : 128*9 ulonglong2          = 18432
//   18432    stats    : 128 * {i64 sum, i64 sq}   = 2048
//   20480    scale/shift float2[128]              = 1024
//   32768    xpack    : 64*3136 ulonglong2        = 3211264  (ends 3244032)
//   3244032  y16      : TOT * int16               = 51380224 (ends 54624256)
#define WS_WPACK 0
#define WS_STATS 18432
#define WS_SS    20480
#define WS_XPACK 32768
#define WS_Y16   3244032
#define WS_NEED  (3244032 + (size_t)TOT*2)

__global__ void pack_w_kernel(const float* __restrict__ w, ulonglong2* __restrict__ wpack) {
    int t = blockIdx.x * 256 + threadIdx.x;
    if (t >= OO * 9) return;
    int o = t / 9, tap = t % 9;
    const float* wp = w + (size_t)o * CC * 9 + tap;   // OIHW: stride 9 between channels
    unsigned long long lo = 0, hi = 0;
    #pragma unroll 4
    for (int c = 0; c < 64; ++c) lo |= (unsigned long long)(wp[c * 9] > 0.0f) << c;
    #pragma unroll 4
    for (int c = 0; c < 64; ++c) hi |= (unsigned long long)(wp[(c + 64) * 9] > 0.0f) << c;
    wpack[t] = make_ulonglong2(lo, hi);
}

__global__ void pack_x_kernel(const float* __restrict__ x, ulonglong2* __restrict__ xpack) {
    int n = blockIdx.y;
    int p = blockIdx.x * 256 + threadIdx.x;
    if (p >= PIX) return;
    const float* xp = x + (size_t)n * CC * PIX + p;
    unsigned long long lo = 0, hi = 0;
    #pragma unroll 8
    for (int c = 0; c < 64; ++c) lo |= (unsigned long long)(xp[(size_t)c * PIX] > 0.0f) << c;
    #pragma unroll 8
    for (int c = 0; c < 64; ++c) hi |= (unsigned long long)(xp[(size_t)(c + 64) * PIX] > 0.0f) << c;
    xpack[n * PIX + p] = make_ulonglong2(lo, hi);
}

// MODE 0: stats only.  MODE 1: stats + y as int16 to ws.  MODE 2: normalized float out (recompute path).
// Block: 256 threads = 32 output channels x 8 w-segments(7 px). Grid: (4 ogroups, 4 h-strips(14 rows), 64 n).
// Per thread: 3-row x 9-word register sliding window; zero-padded border words fixed by
// exact corrections f(tap) = 128 - 2*popc(w_tap).
template <int MODE>
__global__ __launch_bounds__(256, 2) void conv_kernel(
    const ulonglong2* __restrict__ xpack,
    const ulonglong2* __restrict__ wpack,
    unsigned long long* stats,
    const float2* __restrict__ ss,
    short* __restrict__ y16,
    float* __restrict__ out)
{
    const int og = blockIdx.x;
    const int strip = blockIdx.y;
    const int n = blockIdx.z;
    const int tid = threadIdx.x;
    const int o_idx = tid & 31;
    const int wseg = tid >> 5;         // 0..7
    const int o = og * 32 + o_idx;
    const int w0 = wseg * 7;
    const int h0 = strip * 14;

    ulonglong2 wt[9];
    #pragma unroll
    for (int t = 0; t < 9; ++t) wt[t] = wpack[o * 9 + t];

    int f[9];
    #pragma unroll
    for (int t = 0; t < 9; ++t) f[t] = 128 - 2 * (__popcll(wt[t].x) + __popcll(wt[t].y));
    const int cr0 = f[0] + f[1] + f[2];
    const int cr2 = f[6] + f[7] + f[8];
    const int cc0 = f[0] + f[3] + f[6];
    const int cc2 = f[2] + f[5] + f[8];

    float scale = 0.f, shift = 0.f;
    if (MODE == 2) { float2 v = ss[o]; scale = v.x; shift = v.y; }

    const ulonglong2* xp = xpack + n * PIX;

    ulonglong2 rA[9], rB[9], rC[9];
    auto loadRow = [&](ulonglong2* R, int r) {
        if (r < 0 || r >= HH) {
            #pragma unroll
            for (int i = 0; i < 9; ++i) R[i] = make_ulonglong2(0ULL, 0ULL);
        } else {
            #pragma unroll
            for (int i = 0; i < 9; ++i) {
                int wp = w0 - 1 + i;
                R[i] = (wp >= 0 && wp < WW) ? xp[r * WW + wp] : make_ulonglong2(0ULL, 0ULL);
            }
        }
    };

    loadRow(rA, h0 - 1);
    loadRow(rB, h0);

    int ysum = 0, ysq = 0;

    for (int h = h0; h < h0 + 14; ++h) {
        loadRow(rC, h + 1);
        #pragma unroll
        for (int j = 0; j < 7; ++j) {
            int mis = 0;
            #pragma unroll
            for (int kw = 0; kw < 3; ++kw) {
                ulonglong2 a = rA[j + kw];
                mis += __popcll(a.x ^ wt[kw].x) + __popcll(a.y ^ wt[kw].y);
                ulonglong2 b = rB[j + kw];
                mis += __popcll(b.x ^ wt[3 + kw].x) + __popcll(b.y ^ wt[3 + kw].y);
                ulonglong2 c = rC[j + kw];
                mis += __popcll(c.x ^ wt[6 + kw].x) + __popcll(c.y ^ wt[6 + kw].y);
            }
            int y = 1152 - 2 * mis;
            int corr = 0;
            if (h == 0) corr += cr0;
            if (h == HH - 1) corr += cr2;
            if (j == 0 && wseg == 0) {
                corr += cc0;
                if (h == 0) corr -= f[0];
                if (h == HH - 1) corr -= f[6];
            }
            if (j == 6 && wseg == 7) {
                corr += cc2;
                if (h == 0) corr -= f[2];
                if (h == HH - 1) corr -= f[8];
            }
            y -= corr;
            if (MODE != 2) { ysum += y; ysq += y * y; }
            size_t oidx = ((size_t)(n * OO + o) * HH + h) * WW + (w0 + j);
            if (MODE == 1) y16[oidx] = (short)y;
            if (MODE == 2) out[oidx] = (float)y * scale + shift;
        }
        #pragma unroll
        for (int i = 0; i < 9; ++i) { rA[i] = rB[i]; rB[i] = rC[i]; }
    }

    if (MODE != 2) {
        __shared__ int s_sum[256];
        __shared__ int s_sq[256];
        s_sum[tid] = ysum;
        s_sq[tid] = ysq;
        __syncthreads();
        if (tid < 32) {
            long long ts = 0, tq = 0;
            #pragma unroll
            for (int k = 0; k < 8; ++k) { ts += s_sum[tid + 32 * k]; tq += s_sq[tid + 32 * k]; }
            int oo = og * 32 + tid;
            atomicAdd(&stats[oo * 2 + 0], (unsigned long long)ts);
            atomicAdd(&stats[oo * 2 + 1], (unsigned long long)tq);
        }
    }
}

__global__ void finalize_kernel(const unsigned long long* __restrict__ stats,
                                const float* __restrict__ gamma,
                                const float* __restrict__ beta,
                                float2* __restrict__ ss) {
    int c = threadIdx.x;
    if (c >= 128) return;
    long long s = (long long)stats[c * 2 + 0];
    long long q = (long long)stats[c * 2 + 1];
    double mean = (double)s / (double)CNT;
    double var = (double)q / (double)CNT - mean * mean;
    double inv = 1.0 / sqrt(var + 1e-5);
    double g = (double)gamma[c];
    float sc = (float)(g * inv);
    float sh = (float)((double)beta[c] - mean * g * inv);
    ss[c] = make_float2(sc, sh);
}

// 8 elements/thread; 3136 % 8 == 0 so a group never crosses a channel boundary.
__global__ void norm_kernel(const short* __restrict__ y16,
                            const float2* __restrict__ ss,
                            float* __restrict__ out) {
    size_t g = (size_t)blockIdx.x * 256 + threadIdx.x;
    size_t e = g * 8;
    unsigned int chan = (unsigned int)((e / PIX) & 127);
    float2 v = ss[chan];
    int4 raw = *reinterpret_cast<const int4*>(y16 + e);
    float4 o0, o1;
    o0.x = (float)(short)(raw.x & 0xffff) * v.x + v.y;
    o0.y = (float)(short)(raw.x >> 16)    * v.x + v.y;
    o0.z = (float)(short)(raw.y & 0xffff) * v.x + v.y;
    o0.w = (float)(short)(raw.y >> 16)    * v.x + v.y;
    o1.x = (float)(short)(raw.z & 0xffff) * v.x + v.y;
    o1.y = (float)(short)(raw.z >> 16)    * v.x + v.y;
    o1.z = (float)(short)(raw.w & 0xffff) * v.x + v.y;
    o1.w = (float)(short)(raw.w >> 16)    * v.x + v.y;
    *reinterpret_cast<float4*>(out + e) = o0;
    *reinterpret_cast<float4*>(out + e + 4) = o1;
}

extern "C" void kernel_launch(void* const* d_in, const int* in_sizes, int n_in,
                              void* d_out, int out_size, void* d_ws, size_t ws_size,
                              hipStream_t stream) {
    const float* x     = (const float*)d_in[0];
    const float* wgt   = (const float*)d_in[1];
    const float* gamma = (const float*)d_in[2];
    const float* beta  = (const float*)d_in[3];
    float* out = (float*)d_out;
    char* ws = (char*)d_ws;

    ulonglong2* wpack = (ulonglong2*)(ws + WS_WPACK);
    unsigned long long* stats = (unsigned long long*)(ws + WS_STATS);
    float2* ss = (float2*)(ws + WS_SS);
    ulonglong2* xpack = (ulonglong2*)(ws + WS_XPACK);
    short* y16 = (short*)(ws + WS_Y16);

    hipMemsetAsync(stats, 0, 2048, stream);
    pack_w_kernel<<<5, 256, 0, stream>>>(wgt, wpack);
    pack_x_kernel<<<dim3(13, 64), 256, 0, stream>>>(x, xpack);

    if (ws_size >= WS_NEED) {
        conv_kernel<1><<<dim3(4, 4, 64), 256, 0, stream>>>(xpack, wpack, stats, nullptr, y16, nullptr);
        finalize_kernel<<<1, 128, 0, stream>>>(stats, gamma, beta, ss);
        norm_kernel<<<(unsigned)(TOT / 8 / 256), 256, 0, stream>>>(y16, ss, out);
    } else {
        conv_kernel<0><<<dim3(4, 4, 64), 256, 0, stream>>>(xpack, wpack, stats, nullptr, nullptr, nullptr);
        finalize_kernel<<<1, 128, 0, stream>>>(stats, gamma, beta, ss);
        conv_kernel<2><<<dim3(4, 4, 64), 256, 0, stream>>>(xpack, wpack, stats, ss, nullptr, out);
    }
}